// Round 5
// baseline (497.145 us; speedup 1.0000x reference)
//
#include <hip/hip_runtime.h>

typedef int v4i __attribute__((ext_vector_type(4)));

#define M_DIM 4096
#define N_DIM 11008
#define K_DIM 4096
#define KP    (K_DIM / 2)   // packed int32 elements per row (one byte each)
#define KPB   (K_DIM / 2)   // packed BYTES per row after pack pre-pass
#define NKT2  (K_DIM / 128) // 32 K-tiles of 128 k (64 packed bytes)

// ---------------------------------------------------------------------------
// SWAR helpers
// ---------------------------------------------------------------------------
__device__ __forceinline__ unsigned pack2(int p) {
    int lo = (p << 28) >> 28;
    int hi = (p << 24) >> 28;
    return (unsigned)(lo & 0xFF) | ((unsigned)(hi & 0xFF) << 8);
}

__device__ __forceinline__ void unpack_group(int4 p, unsigned &slo, unsigned &shi) {
    unsigned c = ((unsigned)p.x & 0xFFu)
               | (((unsigned)p.y & 0xFFu) << 8)
               | (((unsigned)p.z & 0xFFu) << 16)
               | (((unsigned)p.w & 0xFFu) << 24);
    slo = (c & 0x0F0F0F0Fu) | ((c & 0x08080808u) * 30u);
    unsigned d = c >> 4;
    shi = (d & 0x0F0F0F0Fu) | ((d & 0x08080808u) * 30u);
}

// Per-byte sign-extend of the LOW nibble of each byte of u.
// (s<<5)-(s<<1) == s*30: per-byte 0x08*30=0xF0, exact mod 2^32 (true product
// 0xF0F0F0F0 < 2^32), full-rate shifts instead of v_mul_lo.
__device__ __forceinline__ int sx4(unsigned u) {
    unsigned a = u & 0x0F0F0F0Fu;
    unsigned s = u & 0x08080808u;
    return (int)(a | ((s << 5) - (s << 1)));
}

// 16 packed bytes (raw v4i from LDS) -> two int8 MFMA frags (k-subtile 0, 1).
// Nibble/word permutation is IDENTICAL for A and B => dot product invariant.
__device__ __forceinline__ void unpack16(v4i r, v4i &f0, v4i &f1) {
    unsigned w0 = (unsigned)r[0], w1 = (unsigned)r[1];
    unsigned w2 = (unsigned)r[2], w3 = (unsigned)r[3];
    f0[0] = sx4(w0); f0[1] = sx4(w0 >> 4); f0[2] = sx4(w1); f0[3] = sx4(w1 >> 4);
    f1[0] = sx4(w2); f1[1] = sx4(w2 >> 4); f1[2] = sx4(w3); f1[3] = sx4(w3 >> 4);
}

// ---------------------------------------------------------------------------
// Pass 1 (merged, grid-stride): compress int32 (one packed byte per int) to
// true packed-int4 bytes.  A then B contiguous in d_ws.  16B load -> 4B store.
// A = 8.4 MB, B = 22.5 MB  (was 16.8 + 45.1 int8) -> halves GEMM-side traffic.
// ---------------------------------------------------------------------------
__global__ __launch_bounds__(256) void pack_i4_all(
    const int* __restrict__ inA, const int* __restrict__ inB,
    unsigned* __restrict__ out, int n4A, int n4tot)
{
    for (int idx = blockIdx.x * blockDim.x + threadIdx.x; idx < n4tot;
         idx += gridDim.x * blockDim.x) {
        int4 v;
        if (idx < n4A) v = ((const int4*)inA)[idx];
        else           v = ((const int4*)inB)[idx - n4A];
        out[idx] = ((unsigned)v.x & 0xFFu)
                 | (((unsigned)v.y & 0xFFu) << 8)
                 | (((unsigned)v.z & 0xFFu) << 16)
                 | (((unsigned)v.w & 0xFFu) << 24);
    }
}

// ---------------------------------------------------------------------------
// Pass 2: int4-packed GEMM, 256x256 tile, 512 threads = 8 waves (2 wm x 4 wn),
// each wave 128x64 output, mfma_i32_16x16x64_i8, K-tile = 128 k (64 packed B).
//
// Staging (validated skeleton, rounds 1-4; formulas byte-identical, only the
// row stride is KPB=2048 and a tile covers 128 k): 4-buffer LDS rotation
// (4 x 32 KB), depth-3 prefetch, 4 global_load_lds per STAGE, counted
// s_waitcnt vmcnt(8) + ONE s_barrier per K-tile.
//   - Read hazard: at tile kt entry, vmcnt(8) leaves only kt+1/kt+2's 8 loads
//     in flight -> kt's loads landed (this wave); barrier extends to all waves.
//   - Overwrite hazard: STAGE(kt+3) targets buf[(kt-1)&3]; all waves' ds_reads
//     of kt-1 completed before their kt-1 MFMAs (compiler lgkmcnt), hence
//     before reaching kt's barrier; STAGE issues after that barrier.
//
// In-register unpack: raw frag = 16 packed bytes (ds_read_b128, conflict-free
// fragment-ordered layout, SQ_LDS_BANK_CONFLICT=0 validated) -> unpack16 ->
// two k-subtile frags -> 2 MFMAs.  A/B use the same k-permutation.
// VALU unpack (~48 ops/frag) overlaps the MFMA pipe (separate pipes, m114).
// ---------------------------------------------------------------------------
__global__ __launch_bounds__(512, 2) void gemm_i4p_kernel(
    const unsigned char* __restrict__ A4, const unsigned char* __restrict__ B4,
    const float* __restrict__ sx, const float* __restrict__ sw,
    float* __restrict__ out)
{
    __shared__ v4i smem[8192];                 // 128 KB: 4 buffers x (A 16KB | B 16KB)
    unsigned char* smemAll = (unsigned char*)smem;

    const int t    = threadIdx.x;
    const int lane = t & 63;
    const int w    = t >> 6;      // wave 0..7
    const int wm   = w >> 2;      // 0..1
    const int wn   = w & 3;       // 0..3

    // Bijective XCD swizzle: 688 blocks = 8 * 86 exact.
    const int orig = blockIdx.x;
    const int wgid = (orig & 7) * 86 + (orig >> 3);
    const int bx   = wgid >> 4;        // 0..42  (N tiles)
    const int by   = wgid & 15;        // 0..15  (M tiles)
    const int rowBase = by * 256;
    const int colBase = bx * 256;

    // Staging: thread t stages A-chunks {t, t+512} and B-chunks {t, t+512}.
    // chunk c (0..1023): row = (c>>6)*16 + (c&15), 16B-granule q = (c>>4)&3
    // (4 granules = the row's 64 packed bytes of this K-tile).
    const int cA0 = t, cA1 = t + 512;
    const int rA0 = (cA0 >> 6) * 16 + (cA0 & 15);
    const int rA1 = (cA1 >> 6) * 16 + (cA1 & 15);
    const int qA0 = ((cA0 >> 4) & 3) * 16;
    const int qA1 = ((cA1 >> 4) & 3) * 16;

    const unsigned char* gA0 = A4 + (size_t)(rowBase + rA0) * KPB + qA0;
    const unsigned char* gA1 = A4 + (size_t)(rowBase + rA1) * KPB + qA1;
    const unsigned char* gB0 = B4 + (size_t)(colBase + rA0) * KPB + qA0;
    const unsigned char* gB1 = B4 + (size_t)(colBase + rA1) * KPB + qA1;

    const int oA0 = cA0 * 16;
    const int oA1 = cA1 * 16;
    const int oB0 = 16384 + cA0 * 16;
    const int oB1 = 16384 + cA1 * 16;

    v4i acc[8][4] = {};

#define STAGE_AB(S) do {                                                       \
    unsigned char* _sb = smemAll + (((S) & 3) << 15);                          \
    const int _kb = (S) * 64;                                                  \
    __builtin_amdgcn_global_load_lds(                                          \
        (const __attribute__((address_space(1))) void*)(gA0 + _kb),            \
        (__attribute__((address_space(3))) void*)(_sb + oA0), 16, 0, 0);       \
    __builtin_amdgcn_global_load_lds(                                          \
        (const __attribute__((address_space(1))) void*)(gA1 + _kb),            \
        (__attribute__((address_space(3))) void*)(_sb + oA1), 16, 0, 0);       \
    __builtin_amdgcn_global_load_lds(                                          \
        (const __attribute__((address_space(1))) void*)(gB0 + _kb),            \
        (__attribute__((address_space(3))) void*)(_sb + oB0), 16, 0, 0);       \
    __builtin_amdgcn_global_load_lds(                                          \
        (const __attribute__((address_space(1))) void*)(gB1 + _kb),            \
        (__attribute__((address_space(3))) void*)(_sb + oB1), 16, 0, 0);       \
} while (0)

    // One K-tile: 12 raw ds_read_b128 -> STAGE(kt+3) -> unpack B -> per-mt
    // {unpack A, 8 MFMAs}.  Frag read addresses identical to validated kernel:
    // lane l reads 16 packed B at chunk rt*64 + l  (row rt*16+(l&15),
    // granule l>>4) -> the two k-subtile frags for this (row, lane-quad).
#define TILE(KT, DO_STAGE) do {                                                \
    const unsigned char* _b = smemAll + (((KT) & 3) << 15);                    \
    v4i braw[4], araw[8];                                                      \
    _Pragma("unroll")                                                          \
    for (int nt = 0; nt < 4; ++nt)                                             \
        braw[nt] = *((const v4i*)(_b + 16384 + (((wn * 4 + nt) * 64 + lane) << 4))); \
    _Pragma("unroll")                                                          \
    for (int mt = 0; mt < 8; ++mt)                                             \
        araw[mt] = *((const v4i*)(_b + (((wm * 8 + mt) * 64 + lane) << 4)));   \
    if (DO_STAGE) STAGE_AB((KT) + 3);                                          \
    v4i bf0[4], bf1[4];                                                        \
    _Pragma("unroll")                                                          \
    for (int nt = 0; nt < 4; ++nt) unpack16(braw[nt], bf0[nt], bf1[nt]);       \
    _Pragma("unroll")                                                          \
    for (int mt = 0; mt < 8; ++mt) {                                           \
        v4i a0, a1;                                                            \
        unpack16(araw[mt], a0, a1);                                            \
        __builtin_amdgcn_s_setprio(1);                                         \
        _Pragma("unroll")                                                      \
        for (int nt = 0; nt < 4; ++nt) {                                       \
            acc[mt][nt] = __builtin_amdgcn_mfma_i32_16x16x64_i8(               \
                a0, bf0[nt], acc[mt][nt], 0, 0, 0);                            \
            acc[mt][nt] = __builtin_amdgcn_mfma_i32_16x16x64_i8(               \
                a1, bf1[nt], acc[mt][nt], 0, 0, 0);                            \
        }                                                                      \
        __builtin_amdgcn_s_setprio(0);                                         \
    }                                                                          \
} while (0)

    // Prologue: stage K-tiles 0..2 (12 loads in flight per thread).
    STAGE_AB(0); STAGE_AB(1); STAGE_AB(2);

    // Main loop: drain only the K-tile we are about to read (keep 8 in flight).
    for (int kt = 0; kt < NKT2 - 3; ++kt) {
        asm volatile("s_waitcnt vmcnt(8)" ::: "memory");
        __builtin_amdgcn_s_barrier();
        __builtin_amdgcn_sched_barrier(0);
        TILE(kt, 1);
    }
    // Tail: vmcnt steps 8 -> 4 -> 0.
    asm volatile("s_waitcnt vmcnt(8)" ::: "memory");
    __builtin_amdgcn_s_barrier();
    __builtin_amdgcn_sched_barrier(0);
    TILE(NKT2 - 3, 0);
    asm volatile("s_waitcnt vmcnt(4)" ::: "memory");
    __builtin_amdgcn_s_barrier();
    __builtin_amdgcn_sched_barrier(0);
    TILE(NKT2 - 2, 0);
    asm volatile("s_waitcnt vmcnt(0)" ::: "memory");
    __builtin_amdgcn_s_barrier();
    __builtin_amdgcn_sched_barrier(0);
    TILE(NKT2 - 1, 0);

#undef STAGE_AB
#undef TILE

    // Epilogue. C/D layout (16x16): col = lane&15, row = (lane>>4)*4 + reg.
    const int ccol = lane & 15;
    const int crow = (lane >> 4) * 4;

    float xs[8][4];
    #pragma unroll
    for (int mt = 0; mt < 8; ++mt)
        #pragma unroll
        for (int r = 0; r < 4; ++r)
            xs[mt][r] = sx[rowBase + wm * 128 + mt * 16 + crow + r];

    #pragma unroll
    for (int nt = 0; nt < 4; ++nt) {
        const int gn = colBase + wn * 64 + nt * 16 + ccol;
        const float wsc = sw[gn];
        #pragma unroll
        for (int mt = 0; mt < 8; ++mt) {
            const int gm = rowBase + wm * 128 + mt * 16 + crow;
            #pragma unroll
            for (int r = 0; r < 4; ++r) {
                float v = (float)acc[mt][nt][r] * xs[mt][r] * wsc;
                out[(size_t)(gm + r) * N_DIM + gn] = v;
            }
        }
    }
}

// ---------------------------------------------------------------------------
// Fallback: fused unpack+GEMM (validated), used only if d_ws is too small.
// ---------------------------------------------------------------------------
__global__ __launch_bounds__(256) void gemm_i4_fused_kernel(
    const int* __restrict__ Aq, const int* __restrict__ Bq,
    const float* __restrict__ sx, const float* __restrict__ sw,
    float* __restrict__ out)
{
    __shared__ v4i smem[1024];
    unsigned char* smemA = (unsigned char*)smem;
    unsigned char* smemB = smemA + 8192;

    const int t    = threadIdx.x;
    const int lane = t & 63;
    const int w    = t >> 6;
    const int wm   = w >> 1;
    const int wn   = w & 1;
    const int rowBase = blockIdx.y * 128;
    const int colBase = blockIdx.x * 128;

    const int c0 = t, c1 = t + 256;
    const int r0 = (c0 >> 6) * 16 + (c0 & 15);
    const int r1 = (c1 >> 6) * 16 + (c1 & 15);
    const int q0 = (c0 >> 4) & 3;
    const int q1 = (c1 >> 4) & 3;

    const int* gA0 = Aq + (size_t)(rowBase + r0) * KP + q0 * 8;
    const int* gA1 = Aq + (size_t)(rowBase + r1) * KP + q1 * 8;
    const int* gB0 = Bq + (size_t)(colBase + r0) * KP + q0 * 8;
    const int* gB1 = Bq + (size_t)(colBase + r1) * KP + q1 * 8;

    v4i* lA0 = (v4i*)(smemA + c0 * 16);
    v4i* lA1 = (v4i*)(smemA + c1 * 16);
    v4i* lB0 = (v4i*)(smemB + c0 * 16);
    v4i* lB1 = (v4i*)(smemB + c1 * 16);

    v4i acc[4][4] = {};

    for (int kb = 0; kb < K_DIM; kb += 64) {
        const int kp = kb >> 1;
        int4 a00 = *(const int4*)(gA0 + kp);
        int4 a01 = *(const int4*)(gA0 + kp + 4);
        int4 a10 = *(const int4*)(gA1 + kp);
        int4 a11 = *(const int4*)(gA1 + kp + 4);
        int4 b00 = *(const int4*)(gB0 + kp);
        int4 b01 = *(const int4*)(gB0 + kp + 4);
        int4 b10 = *(const int4*)(gB1 + kp);
        int4 b11 = *(const int4*)(gB1 + kp + 4);

        __syncthreads();

        unsigned u0, u1, u2, u3;
        unpack_group(a00, u0, u1); unpack_group(a01, u2, u3);
        *lA0 = (v4i){(int)u0, (int)u1, (int)u2, (int)u3};
        unpack_group(a10, u0, u1); unpack_group(a11, u2, u3);
        *lA1 = (v4i){(int)u0, (int)u1, (int)u2, (int)u3};
        unpack_group(b00, u0, u1); unpack_group(b01, u2, u3);
        *lB0 = (v4i){(int)u0, (int)u1, (int)u2, (int)u3};
        unpack_group(b10, u0, u1); unpack_group(b11, u2, u3);
        *lB1 = (v4i){(int)u0, (int)u1, (int)u2, (int)u3};

        __syncthreads();

        v4i af[4], bf[4];
        #pragma unroll
        for (int mt = 0; mt < 4; ++mt)
            af[mt] = *((const v4i*)(smemA + ((wm * 4 + mt) * 64 + lane) * 16));
        #pragma unroll
        for (int nt = 0; nt < 4; ++nt)
            bf[nt] = *((const v4i*)(smemB + ((wn * 4 + nt) * 64 + lane) * 16));

        #pragma unroll
        for (int mt = 0; mt < 4; ++mt)
            #pragma unroll
            for (int nt = 0; nt < 4; ++nt)
                acc[mt][nt] = __builtin_amdgcn_mfma_i32_16x16x64_i8(
                    af[mt], bf[nt], acc[mt][nt], 0, 0, 0);
    }

    const int ccol = lane & 15;
    const int crow = (lane >> 4) * 4;

    float xs[4][4];
    #pragma unroll
    for (int mt = 0; mt < 4; ++mt)
        #pragma unroll
        for (int r = 0; r < 4; ++r)
            xs[mt][r] = sx[rowBase + wm * 64 + mt * 16 + crow + r];

    #pragma unroll
    for (int nt = 0; nt < 4; ++nt) {
        const int gn = colBase + wn * 64 + nt * 16 + ccol;
        const float wsc = sw[gn];
        #pragma unroll
        for (int mt = 0; mt < 4; ++mt) {
            const int gm = rowBase + wm * 64 + mt * 16 + crow;
            #pragma unroll
            for (int r = 0; r < 4; ++r) {
                float v = (float)acc[mt][nt][r] * xs[mt][r] * wsc;
                out[(size_t)(gm + r) * N_DIM + gn] = v;
            }
        }
    }
}

extern "C" void kernel_launch(void* const* d_in, const int* in_sizes, int n_in,
                              void* d_out, int out_size, void* d_ws, size_t ws_size,
                              hipStream_t stream) {
    (void)in_sizes; (void)n_in; (void)out_size;
    const int*   x_q = (const int*)d_in[0];
    const float* sx  = (const float*)d_in[1];
    const int*   w_q = (const int*)d_in[2];
    const float* sw  = (const float*)d_in[3];
    float*       out = (float*)d_out;

    const size_t needA = (size_t)M_DIM * KPB;          // 8.4 MB packed
    const size_t needB = (size_t)N_DIM * KPB;          // 22.5 MB packed
    if (ws_size >= needA + needB) {
        unsigned char* A4 = (unsigned char*)d_ws;
        unsigned char* B4 = A4 + needA;
        const int n4A = M_DIM * KP / 4;   // 2,097,152
        const int n4B = N_DIM * KP / 4;   // 5,636,096
        const int n4T = n4A + n4B;        // 7,733,248
        pack_i4_all<<<2048, 256, 0, stream>>>(x_q, w_q, (unsigned*)d_ws, n4A, n4T);
        // 256x256 tiles: 43 x 16 = 688 blocks = 8 * 86 (XCD swizzle exact).
        gemm_i4p_kernel<<<688, 512, 0, stream>>>(A4, B4, sx, sw, out);
    } else {
        dim3 grid(N_DIM / 128, M_DIM / 128);   // 86 x 32, exact
        gemm_i4_fused_kernel<<<grid, 256, 0, stream>>>(x_q, w_q, sx, sw, out);
    }
}

// Round 6
// 477.990 us; speedup vs baseline: 1.0401x; 1.0401x over previous
//
#include <hip/hip_runtime.h>

typedef int v4i __attribute__((ext_vector_type(4)));

#define M_DIM 4096
#define N_DIM 11008
#define K_DIM 4096
#define KP    (K_DIM / 2)   // packed int32 elements per row (one byte each)
#define NKT   (K_DIM / 64)  // 64 K-tiles of 64

// ---------------------------------------------------------------------------
// SWAR sign-extend helpers
// ---------------------------------------------------------------------------
__device__ __forceinline__ unsigned pack2(int p) {
    int lo = (p << 28) >> 28;   // sign-extended low nibble
    int hi = (p << 24) >> 28;   // sign-extended high nibble
    return (unsigned)(lo & 0xFF) | ((unsigned)(hi & 0xFF) << 8);
}

__device__ __forceinline__ void unpack_group(int4 p, unsigned &slo, unsigned &shi) {
    unsigned c = ((unsigned)p.x & 0xFFu)
               | (((unsigned)p.y & 0xFFu) << 8)
               | (((unsigned)p.z & 0xFFu) << 16)
               | (((unsigned)p.w & 0xFFu) << 24);
    slo = (c & 0x0F0F0F0Fu) | ((c & 0x08080808u) * 30u);
    unsigned d = c >> 4;
    shi = (d & 0x0F0F0F0Fu) | ((d & 0x08080808u) * 30u);
}

// ---------------------------------------------------------------------------
// Pass 1: unpack BOTH x_q and weight into contiguous int8 regions of d_ws
// (A8 then B8).  Merged + FULL grid (round-1 config: best measured gap),
// vectorized to 32 B loads / 16 B stores per thread (G13).
// Pair p covers int4-groups {2p, 2p+1}; n4A is even so no pair straddles
// the A/B boundary.  Output bytes identical to the validated round-2 layout.
// ---------------------------------------------------------------------------
__global__ __launch_bounds__(256) void unpack_i4_all2(
    const int* __restrict__ inA, const int* __restrict__ inB,
    uint4* __restrict__ out, int n2A, int n2tot)
{
    int idx = blockIdx.x * blockDim.x + threadIdx.x;   // pair index
    if (idx >= n2tot) return;
    const int4* src;
    int base;
    if (idx < n2A) { src = (const int4*)inA; base = idx * 2; }
    else           { src = (const int4*)inB; base = (idx - n2A) * 2; }
    int4 v0 = src[base];
    int4 v1 = src[base + 1];
    uint4 o;
    o.x = pack2(v0.x) | (pack2(v0.y) << 16);
    o.y = pack2(v0.z) | (pack2(v0.w) << 16);
    o.z = pack2(v1.x) | (pack2(v1.y) << 16);
    o.w = pack2(v1.z) | (pack2(v1.w) << 16);
    out[idx] = o;
}

// ---------------------------------------------------------------------------
// Pass 2: int8 GEMM, 256x256 tile, 512 threads = 8 waves (2 wm x 4 wn), each
// wave a 128x64 output via 8x4 tiles of mfma_i32_16x16x64_i8, BK=64.
// VERBATIM round-2 kernel (best measured: 242.4 us).
//
// Sync skeleton: 4-buffer LDS rotation, depth-3 K-tile prefetch, counted
// s_waitcnt vmcnt(8), ONE raw s_barrier per K-tile:
//   - Read hazard: at K-tile kt entry, vmcnt(8) leaves only kt+1/kt+2's 8
//     loads in flight -> kt's 4 loads landed for THIS wave; the barrier then
//     guarantees it for ALL waves before any ds_read of buf[kt&3].
//   - Overwrite hazard: STAGE(kt+3) targets buf[(kt+3)&3] = buf[(kt-1)&3];
//     every wave's ds_reads of kt-1 completed before its kt-1 MFMAs
//     (lgkmcnt) and hence before it reached kt's barrier; STAGE is issued
//     after that barrier.
//
// LDS fragment-ordered (conflict-free, global_load_lds-compatible):
// buffer = 32 KB (A 16 KB | B 16 KB); chunk c = rowTile*64 + lane, 16 B.
// mfma_i32_16x16x64_i8 A/B frag: lane l holds row l&15, k-bytes (l>>4)*16.
// ---------------------------------------------------------------------------
__global__ __launch_bounds__(512, 2) void gemm_i8_kernel(
    const unsigned char* __restrict__ A8, const unsigned char* __restrict__ B8,
    const float* __restrict__ sx, const float* __restrict__ sw,
    float* __restrict__ out)
{
    __shared__ v4i smem[8192];                 // 128 KB: 4 buffers x (A 16KB | B 16KB)
    unsigned char* smemAll = (unsigned char*)smem;

    const int t    = threadIdx.x;
    const int lane = t & 63;
    const int w    = t >> 6;      // wave 0..7
    const int wm   = w >> 2;      // 0..1
    const int wn   = w & 3;       // 0..3

    // Bijective XCD swizzle: 688 blocks = 8 * 86 exact.  Consecutive wgids
    // share a B column-panel (bx) -> per-XCD L2 holds the B-panel.
    const int orig = blockIdx.x;
    const int wgid = (orig & 7) * 86 + (orig >> 3);
    const int bx   = wgid >> 4;        // 0..42  (N tiles)
    const int by   = wgid & 15;        // 0..15  (M tiles)
    const int rowBase = by * 256;
    const int colBase = bx * 256;

    // Staging: thread t stages A-chunks {t, t+512} and B-chunks {t, t+512}.
    // chunk c: rowTile rt = c>>6, lane l = c&63; row = rt*16 + (l&15),
    // k-byte offset = (l>>4)*16.  Per wave the 64 chunks of a group are
    // contiguous -> LDS dest = wave-uniform base + lane*16 (required).
    const int cA0 = t, cA1 = t + 512;
    const int rA0 = (cA0 >> 6) * 16 + (cA0 & 15);
    const int rA1 = (cA1 >> 6) * 16 + (cA1 & 15);
    const int qA0 = ((cA0 >> 4) & 3) * 16;
    const int qA1 = ((cA1 >> 4) & 3) * 16;

    const unsigned char* gA0 = A8 + (size_t)(rowBase + rA0) * K_DIM + qA0;
    const unsigned char* gA1 = A8 + (size_t)(rowBase + rA1) * K_DIM + qA1;
    const unsigned char* gB0 = B8 + (size_t)(colBase + rA0) * K_DIM + qA0;
    const unsigned char* gB1 = B8 + (size_t)(colBase + rA1) * K_DIM + qA1;

    const int oA0 = cA0 * 16;
    const int oA1 = cA1 * 16;
    const int oB0 = 16384 + cA0 * 16;
    const int oB1 = 16384 + cA1 * 16;

    v4i acc[8][4] = {};

#define STAGE_A(S) do {                                                        \
    unsigned char* _b = smemAll + (((S) & 3) << 15);                           \
    const int _kb = (S) * 64;                                                  \
    __builtin_amdgcn_global_load_lds(                                          \
        (const __attribute__((address_space(1))) void*)(gA0 + _kb),            \
        (__attribute__((address_space(3))) void*)(_b + oA0), 16, 0, 0);        \
    __builtin_amdgcn_global_load_lds(                                          \
        (const __attribute__((address_space(1))) void*)(gA1 + _kb),            \
        (__attribute__((address_space(3))) void*)(_b + oA1), 16, 0, 0);        \
} while (0)

#define STAGE_B(S) do {                                                        \
    unsigned char* _b = smemAll + (((S) & 3) << 15);                           \
    const int _kb = (S) * 64;                                                  \
    __builtin_amdgcn_global_load_lds(                                          \
        (const __attribute__((address_space(1))) void*)(gB0 + _kb),            \
        (__attribute__((address_space(3))) void*)(_b + oB0), 16, 0, 0);        \
    __builtin_amdgcn_global_load_lds(                                          \
        (const __attribute__((address_space(1))) void*)(gB1 + _kb),            \
        (__attribute__((address_space(3))) void*)(_b + oB1), 16, 0, 0);        \
} while (0)

    // COMPUTE(S): 2 phases; stage A-half of (SS) in phase 1, B-half in
    // phase 2.  bf[] stays live across both phases.
#define COMPUTE(S, DO_STAGE, SS) do {                                          \
    const unsigned char* _b = smemAll + (((S) & 3) << 15);                     \
    v4i bf[4];                                                                 \
    _Pragma("unroll")                                                          \
    for (int nt = 0; nt < 4; ++nt)                                             \
        bf[nt] = *((const v4i*)(_b + 16384 + (((wn * 4 + nt) * 64 + lane) << 4))); \
    v4i af0[4];                                                                \
    _Pragma("unroll")                                                          \
    for (int mt = 0; mt < 4; ++mt)                                             \
        af0[mt] = *((const v4i*)(_b + (((wm * 8 + mt) * 64 + lane) << 4)));    \
    if (DO_STAGE) STAGE_A(SS);                                                 \
    __builtin_amdgcn_s_setprio(1);                                             \
    _Pragma("unroll")                                                          \
    for (int mt = 0; mt < 4; ++mt)                                             \
        _Pragma("unroll")                                                      \
        for (int nt = 0; nt < 4; ++nt)                                         \
            acc[mt][nt] = __builtin_amdgcn_mfma_i32_16x16x64_i8(               \
                af0[mt], bf[nt], acc[mt][nt], 0, 0, 0);                        \
    __builtin_amdgcn_s_setprio(0);                                             \
    v4i af1[4];                                                                \
    _Pragma("unroll")                                                          \
    for (int mt = 0; mt < 4; ++mt)                                             \
        af1[mt] = *((const v4i*)(_b + (((wm * 8 + 4 + mt) * 64 + lane) << 4))); \
    if (DO_STAGE) STAGE_B(SS);                                                 \
    __builtin_amdgcn_s_setprio(1);                                             \
    _Pragma("unroll")                                                          \
    for (int mt = 0; mt < 4; ++mt)                                             \
        _Pragma("unroll")                                                      \
        for (int nt = 0; nt < 4; ++nt)                                         \
            acc[4 + mt][nt] = __builtin_amdgcn_mfma_i32_16x16x64_i8(           \
                af1[mt], bf[nt], acc[4 + mt][nt], 0, 0, 0);                    \
    __builtin_amdgcn_s_setprio(0);                                             \
} while (0)

    // Prologue: stage K-tiles 0..2 (12 loads in flight per thread).
    STAGE_A(0); STAGE_B(0);
    STAGE_A(1); STAGE_B(1);
    STAGE_A(2); STAGE_B(2);

    // Main loop: drain only the K-tile we are about to read (keep 8 in flight).
    for (int kt = 0; kt < NKT - 3; ++kt) {
        asm volatile("s_waitcnt vmcnt(8)" ::: "memory");
        __builtin_amdgcn_s_barrier();
        __builtin_amdgcn_sched_barrier(0);
        COMPUTE(kt, 1, kt + 3);
    }
    // Tail: step the drain down 8 -> 4 -> 0.
    asm volatile("s_waitcnt vmcnt(8)" ::: "memory");
    __builtin_amdgcn_s_barrier();
    __builtin_amdgcn_sched_barrier(0);
    COMPUTE(NKT - 3, 0, 0);
    asm volatile("s_waitcnt vmcnt(4)" ::: "memory");
    __builtin_amdgcn_s_barrier();
    __builtin_amdgcn_sched_barrier(0);
    COMPUTE(NKT - 2, 0, 0);
    asm volatile("s_waitcnt vmcnt(0)" ::: "memory");
    __builtin_amdgcn_s_barrier();
    __builtin_amdgcn_sched_barrier(0);
    COMPUTE(NKT - 1, 0, 0);

#undef STAGE_A
#undef STAGE_B
#undef COMPUTE

    // Epilogue. C/D layout (16x16): col = lane&15, row = (lane>>4)*4 + reg.
    const int ccol = lane & 15;
    const int crow = (lane >> 4) * 4;

    float xs[8][4];
    #pragma unroll
    for (int mt = 0; mt < 8; ++mt)
        #pragma unroll
        for (int r = 0; r < 4; ++r)
            xs[mt][r] = sx[rowBase + wm * 128 + mt * 16 + crow + r];

    #pragma unroll
    for (int nt = 0; nt < 4; ++nt) {
        const int gn = colBase + wn * 64 + nt * 16 + ccol;
        const float wsc = sw[gn];
        #pragma unroll
        for (int mt = 0; mt < 8; ++mt) {
            const int gm = rowBase + wm * 128 + mt * 16 + crow;
            #pragma unroll
            for (int r = 0; r < 4; ++r) {
                float v = (float)acc[mt][nt][r] * xs[mt][r] * wsc;
                out[(size_t)(gm + r) * N_DIM + gn] = v;
            }
        }
    }
}

// ---------------------------------------------------------------------------
// Fallback: fused unpack+GEMM (validated), used only if d_ws is too small.
// ---------------------------------------------------------------------------
__global__ __launch_bounds__(256) void gemm_i4_fused_kernel(
    const int* __restrict__ Aq, const int* __restrict__ Bq,
    const float* __restrict__ sx, const float* __restrict__ sw,
    float* __restrict__ out)
{
    __shared__ v4i smem[1024];
    unsigned char* smemA = (unsigned char*)smem;
    unsigned char* smemB = smemA + 8192;

    const int t    = threadIdx.x;
    const int lane = t & 63;
    const int w    = t >> 6;
    const int wm   = w >> 1;
    const int wn   = w & 1;
    const int rowBase = blockIdx.y * 128;
    const int colBase = blockIdx.x * 128;

    const int c0 = t, c1 = t + 256;
    const int r0 = (c0 >> 6) * 16 + (c0 & 15);
    const int r1 = (c1 >> 6) * 16 + (c1 & 15);
    const int q0 = (c0 >> 4) & 3;
    const int q1 = (c1 >> 4) & 3;

    const int* gA0 = Aq + (size_t)(rowBase + r0) * KP + q0 * 8;
    const int* gA1 = Aq + (size_t)(rowBase + r1) * KP + q1 * 8;
    const int* gB0 = Bq + (size_t)(colBase + r0) * KP + q0 * 8;
    const int* gB1 = Bq + (size_t)(colBase + r1) * KP + q1 * 8;

    v4i* lA0 = (v4i*)(smemA + c0 * 16);
    v4i* lA1 = (v4i*)(smemA + c1 * 16);
    v4i* lB0 = (v4i*)(smemB + c0 * 16);
    v4i* lB1 = (v4i*)(smemB + c1 * 16);

    v4i acc[4][4] = {};

    for (int kb = 0; kb < K_DIM; kb += 64) {
        const int kp = kb >> 1;
        int4 a00 = *(const int4*)(gA0 + kp);
        int4 a01 = *(const int4*)(gA0 + kp + 4);
        int4 a10 = *(const int4*)(gA1 + kp);
        int4 a11 = *(const int4*)(gA1 + kp + 4);
        int4 b00 = *(const int4*)(gB0 + kp);
        int4 b01 = *(const int4*)(gB0 + kp + 4);
        int4 b10 = *(const int4*)(gB1 + kp);
        int4 b11 = *(const int4*)(gB1 + kp + 4);

        __syncthreads();

        unsigned u0, u1, u2, u3;
        unpack_group(a00, u0, u1); unpack_group(a01, u2, u3);
        *lA0 = (v4i){(int)u0, (int)u1, (int)u2, (int)u3};
        unpack_group(a10, u0, u1); unpack_group(a11, u2, u3);
        *lA1 = (v4i){(int)u0, (int)u1, (int)u2, (int)u3};
        unpack_group(b00, u0, u1); unpack_group(b01, u2, u3);
        *lB0 = (v4i){(int)u0, (int)u1, (int)u2, (int)u3};
        unpack_group(b10, u0, u1); unpack_group(b11, u2, u3);
        *lB1 = (v4i){(int)u0, (int)u1, (int)u2, (int)u3};

        __syncthreads();

        v4i af[4], bf[4];
        #pragma unroll
        for (int mt = 0; mt < 4; ++mt)
            af[mt] = *((const v4i*)(smemA + ((wm * 4 + mt) * 64 + lane) * 16));
        #pragma unroll
        for (int nt = 0; nt < 4; ++nt)
            bf[nt] = *((const v4i*)(smemB + ((wn * 4 + nt) * 64 + lane) * 16));

        #pragma unroll
        for (int mt = 0; mt < 4; ++mt)
            #pragma unroll
            for (int nt = 0; nt < 4; ++nt)
                acc[mt][nt] = __builtin_amdgcn_mfma_i32_16x16x64_i8(
                    af[mt], bf[nt], acc[mt][nt], 0, 0, 0);
    }

    const int ccol = lane & 15;
    const int crow = (lane >> 4) * 4;

    float xs[4][4];
    #pragma unroll
    for (int mt = 0; mt < 4; ++mt)
        #pragma unroll
        for (int r = 0; r < 4; ++r)
            xs[mt][r] = sx[rowBase + wm * 64 + mt * 16 + crow + r];

    #pragma unroll
    for (int nt = 0; nt < 4; ++nt) {
        const int gn = colBase + wn * 64 + nt * 16 + ccol;
        const float wsc = sw[gn];
        #pragma unroll
        for (int mt = 0; mt < 4; ++mt) {
            const int gm = rowBase + wm * 64 + mt * 16 + crow;
            #pragma unroll
            for (int r = 0; r < 4; ++r) {
                float v = (float)acc[mt][nt][r] * xs[mt][r] * wsc;
                out[(size_t)(gm + r) * N_DIM + gn] = v;
            }
        }
    }
}

extern "C" void kernel_launch(void* const* d_in, const int* in_sizes, int n_in,
                              void* d_out, int out_size, void* d_ws, size_t ws_size,
                              hipStream_t stream) {
    (void)in_sizes; (void)n_in; (void)out_size;
    const int*   x_q = (const int*)d_in[0];
    const float* sx  = (const float*)d_in[1];
    const int*   w_q = (const int*)d_in[2];
    const float* sw  = (const float*)d_in[3];
    float*       out = (float*)d_out;

    const size_t needA = (size_t)M_DIM * K_DIM;        // 16.8 MB int8
    const size_t needB = (size_t)N_DIM * K_DIM;        // 45.1 MB int8
    if (ws_size >= needA + needB) {
        unsigned char* A8 = (unsigned char*)d_ws;
        unsigned char* B8 = A8 + needA;
        const int n4A = M_DIM * KP / 4;   // 2,097,152 (even)
        const int n4B = N_DIM * KP / 4;   // 5,636,096
        const int n2A = n4A / 2;          // 1,048,576
        const int n2T = (n4A + n4B) / 2;  // 3,866,624 = 15104 * 256 (exact)
        unpack_i4_all2<<<n2T / 256, 256, 0, stream>>>(
            x_q, w_q, (uint4*)d_ws, n2A, n2T);
        // 256x256 tiles: 43 x 16 = 688 blocks = 8 * 86 (XCD swizzle exact).
        gemm_i8_kernel<<<688, 512, 0, stream>>>(A8, B8, sx, sw, out);
    } else {
        dim3 grid(N_DIM / 128, M_DIM / 128);   // 86 x 32, exact
        gemm_i4_fused_kernel<<<grid, 256, 0, stream>>>(x_q, w_q, sx, sw, out);
    }
}